// Round 1
// baseline (1842.949 us; speedup 1.0000x reference)
//
#include <hip/hip_runtime.h>
#include <math.h>

#define N_NODES 50000
#define N_EDGES 400000
#define HID 128
#define NH 8
#define HS 16
#define TN 8
#define NR 8

// ---- ordered-uint encoding for float atomicMax ----
__device__ __forceinline__ unsigned int enc_f(float f) {
    unsigned int b = __float_as_uint(f);
    unsigned int mask = (b & 0x80000000u) ? 0xFFFFFFFFu : 0x80000000u;
    return b ^ mask;
}
__device__ __forceinline__ float dec_f(unsigned int u) {
    unsigned int mask = (u & 0x80000000u) ? 0x80000000u : 0xFFFFFFFFu;
    return __uint_as_float(u ^ mask);
}
#define ENC_NEG_INF 0x007FFFFFu  // enc(-inf)

__global__ void init_amax_kernel(unsigned int* __restrict__ amax) {
    int i = blockIdx.x * 256 + threadIdx.x;
    if (i < N_NODES * NH) amax[i] = ENC_NEG_INF;
}

// One block per node, 128 threads; thread j computes output element j of K,Q,V.
__global__ void kqv_kernel(const float* __restrict__ x, const int* __restrict__ ntype,
                           const float* __restrict__ Wk, const float* __restrict__ Wq,
                           const float* __restrict__ Wv,
                           float* __restrict__ K, float* __restrict__ Q, float* __restrict__ V) {
    int n = blockIdx.x, j = threadIdx.x;
    __shared__ float xs[HID];
    xs[j] = x[n * HID + j];
    __syncthreads();
    int t = ntype[n];
    const float* wk = Wk + (size_t)t * HID * HID;
    const float* wq = Wq + (size_t)t * HID * HID;
    const float* wv = Wv + (size_t)t * HID * HID;
    float ak = 0.f, aq = 0.f, av = 0.f;
#pragma unroll 4
    for (int i = 0; i < HID; ++i) {
        float xv = xs[i];
        ak = fmaf(xv, wk[i * HID + j], ak);
        aq = fmaf(xv, wq[i * HID + j], aq);
        av = fmaf(xv, wv[i * HID + j], av);
    }
    int o = n * HID + j;
    K[o] = ak; Q[o] = aq; V[o] = av;
}

// 16 lanes per (edge, head). lane = output dim o.
// a[e,h] = sum_o ( sum_i k[i] * Watt[h,r,i,o] ) * q[o] * pri[h,r] / 4
__global__ void edge_score_kernel(const float* __restrict__ K, const float* __restrict__ Q,
                                  const int* __restrict__ src, const int* __restrict__ dst,
                                  const int* __restrict__ etype,
                                  const float* __restrict__ Watt, const float* __restrict__ pri,
                                  float* __restrict__ a_out, unsigned int* __restrict__ amax) {
    int gid = blockIdx.x * 16 + (threadIdx.x >> 4);
    int lane = threadIdx.x & 15;
    int e = gid >> 3, h = gid & 7;
    int s = src[e], d = dst[e], r = etype[e];
    float k_i = K[s * HID + h * HS + lane];
    float q_o = Q[d * HID + h * HS + lane];
    const float* W = Watt + (size_t)(h * NR + r) * HS * HS;
    float kw = 0.f;
#pragma unroll
    for (int i = 0; i < HS; ++i)
        kw = fmaf(__shfl(k_i, i, HS), W[i * HS + lane], kw);
    float val = kw * q_o;
#pragma unroll
    for (int off = 8; off; off >>= 1) val += __shfl_xor(val, off, 16);
    if (lane == 0) {
        float a = val * pri[h * NR + r] * 0.25f;
        a_out[e * NH + h] = a;
        atomicMax(&amax[d * NH + h], enc_f(a));
    }
}

__global__ void softmax_den_kernel(float* __restrict__ a, const int* __restrict__ dst,
                                   const unsigned int* __restrict__ amax,
                                   float* __restrict__ den) {
    int i = blockIdx.x * 256 + threadIdx.x;  // i = e*8 + h, grid covers E*8 exactly
    int e = i >> 3, h = i & 7;
    int d = dst[e];
    float m = dec_f(amax[d * NH + h]);
    float ex = expf(a[i] - m);
    a[i] = ex;
    atomicAdd(&den[d * NH + h], ex);
}

// 16 lanes per (edge, head); m[o] = sum_i v[i]*Wmsg[h,r,i,o]; agg[dst] += alpha*m
__global__ void message_kernel(const float* __restrict__ V, const int* __restrict__ src,
                               const int* __restrict__ dst, const int* __restrict__ etype,
                               const float* __restrict__ Wmsg, const float* __restrict__ ex,
                               const float* __restrict__ den, float* __restrict__ agg) {
    int gid = blockIdx.x * 16 + (threadIdx.x >> 4);
    int lane = threadIdx.x & 15;
    int e = gid >> 3, h = gid & 7;
    int s = src[e], d = dst[e], r = etype[e];
    float v_i = V[s * HID + h * HS + lane];
    const float* W = Wmsg + (size_t)(h * NR + r) * HS * HS;
    float m = 0.f;
#pragma unroll
    for (int i = 0; i < HS; ++i)
        m = fmaf(__shfl(v_i, i, HS), W[i * HS + lane], m);
    float alpha = ex[e * NH + h] / (den[d * NH + h] + 1e-16f);
    atomicAdd(&agg[d * HID + h * HS + lane], alpha * m);
}

// typed linear Wa + SiLU + gated residual + LayerNorm. One block per node.
__global__ void out_kernel(const float* __restrict__ agg, const float* __restrict__ xin,
                           const int* __restrict__ ntype, const float* __restrict__ Wa,
                           const float* __restrict__ skip, const float* __restrict__ g,
                           const float* __restrict__ b, float* __restrict__ xout) {
    int n = blockIdx.x, j = threadIdx.x;
    __shared__ float as_[HID];
    __shared__ float red[HID];
    as_[j] = agg[n * HID + j];
    __syncthreads();
    int t = ntype[n];
    const float* wa = Wa + (size_t)t * HID * HID;
    float acc = 0.f;
#pragma unroll 4
    for (int i = 0; i < HID; ++i) acc = fmaf(as_[i], wa[i * HID + j], acc);
    float sil = acc / (1.f + expf(-acc));            // x*sigmoid(x)
    float al = 1.f / (1.f + expf(-skip[t]));
    float o = sil * al + xin[n * HID + j] * (1.f - al);
    // LayerNorm over 128
    red[j] = o; __syncthreads();
    for (int s2 = 64; s2; s2 >>= 1) { if (j < s2) red[j] += red[j + s2]; __syncthreads(); }
    float mu = red[0] * (1.f / HID);
    __syncthreads();
    float dv = o - mu;
    red[j] = dv * dv; __syncthreads();
    for (int s2 = 64; s2; s2 >>= 1) { if (j < s2) red[j] += red[j + s2]; __syncthreads(); }
    float var = red[0] * (1.f / HID);
    xout[n * HID + j] = dv * rsqrtf(var + 1e-5f) * g[j] + b[j];
}

__global__ void ff_kernel(const float* __restrict__ emb, const float* __restrict__ Wff,
                          const float* __restrict__ bff, float* __restrict__ out) {
    int n = blockIdx.x, j = threadIdx.x;
    __shared__ float xs[HID];
    xs[j] = emb[n * HID + j];
    __syncthreads();
    float acc = bff[j];
#pragma unroll 4
    for (int i = 0; i < HID; ++i) acc = fmaf(xs[i], Wff[i * HID + j], acc);
    out[n * HID + j] = acc;
}

extern "C" void kernel_launch(void* const* d_in, const int* in_sizes, int n_in,
                              void* d_out, int out_size, void* d_ws, size_t ws_size,
                              hipStream_t stream) {
    const float* x     = (const float*)d_in[0];
    const int*   eidx  = (const int*)d_in[1];
    const int*   ntype = (const int*)d_in[2];
    const int*   etype = (const int*)d_in[3];
    const float* Wk    = (const float*)d_in[4];
    const float* Wq    = (const float*)d_in[5];
    const float* Wv    = (const float*)d_in[6];
    const float* Wa    = (const float*)d_in[7];
    const float* pri   = (const float*)d_in[8];
    const float* Watt  = (const float*)d_in[9];
    const float* Wmsg  = (const float*)d_in[10];
    const float* skip  = (const float*)d_in[11];
    const float* ln_g  = (const float*)d_in[12];
    const float* ln_b  = (const float*)d_in[13];
    const float* Wff   = (const float*)d_in[14];
    const float* bff   = (const float*)d_in[15];
    const int* src = eidx;
    const int* dst = eidx + N_EDGES;

    char* ws = (char*)d_ws;
    size_t szN = (size_t)N_NODES * HID * sizeof(float);       // 25.6 MB
    float* embA = (float*)(ws);                                // layer-0 output
    float* Kb   = (float*)(ws + szN);                          // K, later aliased as agg
    float* Qb   = (float*)(ws + 2 * szN);                      // Q, later layer-1 output
    float* Vb   = (float*)(ws + 3 * szN);                      // V
    float* abuf = (float*)(ws + 4 * szN);                      // scores -> exp
    unsigned int* amax = (unsigned int*)(ws + 4 * szN + (size_t)N_EDGES * NH * 4);
    float* den  = (float*)((char*)amax + (size_t)N_NODES * NH * 4);

    for (int l = 0; l < 2; ++l) {
        const float* xin = l ? embA : x;
        float* xout = l ? Qb : embA;   // layer-1 result reuses Q buffer (dead after scores)
        const float* Wk_l   = Wk   + (size_t)l * TN * HID * HID;
        const float* Wq_l   = Wq   + (size_t)l * TN * HID * HID;
        const float* Wv_l   = Wv   + (size_t)l * TN * HID * HID;
        const float* Wa_l   = Wa   + (size_t)l * TN * HID * HID;
        const float* Watt_l = Watt + (size_t)l * NH * NR * HS * HS;
        const float* Wmsg_l = Wmsg + (size_t)l * NH * NR * HS * HS;
        const float* pri_l  = pri  + (size_t)l * NH * NR;
        const float* skip_l = skip + (size_t)l * TN;
        const float* g_l    = ln_g + (size_t)l * HID;
        const float* b_l    = ln_b + (size_t)l * HID;

        hipMemsetAsync(den, 0, (size_t)N_NODES * NH * 4, stream);
        init_amax_kernel<<<(N_NODES * NH + 255) / 256, 256, 0, stream>>>(amax);
        kqv_kernel<<<N_NODES, HID, 0, stream>>>(xin, ntype, Wk_l, Wq_l, Wv_l, Kb, Qb, Vb);
        edge_score_kernel<<<N_EDGES * NH / 16, 256, 0, stream>>>(Kb, Qb, src, dst, etype,
                                                                 Watt_l, pri_l, abuf, amax);
        hipMemsetAsync(Kb, 0, szN, stream);   // Kb now becomes agg (K dead after scores)
        softmax_den_kernel<<<N_EDGES * NH / 256, 256, 0, stream>>>(abuf, dst, amax, den);
        message_kernel<<<N_EDGES * NH / 16, 256, 0, stream>>>(Vb, src, dst, etype,
                                                              Wmsg_l, abuf, den, Kb);
        out_kernel<<<N_NODES, HID, 0, stream>>>(Kb, xin, ntype, Wa_l, skip_l, g_l, b_l, xout);
    }
    ff_kernel<<<N_NODES, HID, 0, stream>>>(Qb, Wff, bff, (float*)d_out);
}

// Round 2
// 1614.434 us; speedup vs baseline: 1.1415x; 1.1415x over previous
//
#include <hip/hip_runtime.h>
#include <math.h>

#define N_NODES 50000
#define N_EDGES 400000
#define HID 128
#define NH 8
#define HS 16
#define TN 8
#define NR 8
#define TILE 32
#define MAXTILES 1571            // ceil((50000 + 8*31)/32) upper bound on padded tiles
#define PERM_SZ (MAXTILES * TILE)

// ---- ordered-uint encoding for float atomicMax ----
__device__ __forceinline__ unsigned int enc_f(float f) {
    unsigned int b = __float_as_uint(f);
    unsigned int mask = (b & 0x80000000u) ? 0xFFFFFFFFu : 0x80000000u;
    return b ^ mask;
}
__device__ __forceinline__ float dec_f(unsigned int u) {
    unsigned int mask = (u & 0x80000000u) ? 0x80000000u : 0xFFFFFFFFu;
    return __uint_as_float(u ^ mask);
}
#define ENC_NEG_INF 0x007FFFFFu

__global__ void init_amax_kernel(unsigned int* __restrict__ amax) {
    int i = blockIdx.x * 256 + threadIdx.x;
    if (i < N_NODES * NH) amax[i] = ENC_NEG_INF;
}

// ---------- type sort (counting sort, padded segments of TILE) ----------
__global__ void hist_kernel(const int* __restrict__ ntype, int* __restrict__ cnt) {
    int i = blockIdx.x * 256 + threadIdx.x;
    if (i < N_NODES) atomicAdd(&cnt[ntype[i]], 1);
}
__global__ void scan_kernel(const int* __restrict__ cnt, int* __restrict__ cursor) {
    if (threadIdx.x == 0 && blockIdx.x == 0) {
        int acc = 0;
        for (int t = 0; t < TN; ++t) {
            cursor[t] = acc;
            acc += ((cnt[t] + TILE - 1) / TILE) * TILE;
        }
    }
}
__global__ void scatter_kernel(const int* __restrict__ ntype, int* __restrict__ cursor,
                               int* __restrict__ perm) {
    int i = blockIdx.x * 256 + threadIdx.x;
    if (i < N_NODES) {
        int p = atomicAdd(&cursor[ntype[i]], 1);
        perm[p] = i;
    }
}

// ---------- tiled typed GEMM: 32 nodes x 128 outs, 3 matrices (K,Q,V) ----------
__global__ __launch_bounds__(256) void gemm3_kernel(
    const float* __restrict__ x, const int* __restrict__ perm, const int* __restrict__ ntype,
    const float* __restrict__ Wk, const float* __restrict__ Wq, const float* __restrict__ Wv,
    float* __restrict__ K, float* __restrict__ Q, float* __restrict__ V) {
    __shared__ float xs[TILE][HID];
    __shared__ int nodes[TILE];
    int tid = threadIdx.x;
    const int* pp = perm + blockIdx.x * TILE;
    if (tid < TILE) nodes[tid] = pp[tid];
    __syncthreads();
    if (nodes[0] < 0) return;
    int t = ntype[nodes[0]];
    // stage x rows (gathered) into LDS
#pragma unroll
    for (int c = 0; c < 4; ++c) {
        int v = tid + c * 256;            // float4 index 0..1023
        int ns = v >> 5, ii = (v & 31) * 4;
        int node = nodes[ns];
        float4 val = (node >= 0) ? *(const float4*)(x + (size_t)node * HID + ii)
                                 : make_float4(0.f, 0.f, 0.f, 0.f);
        *(float4*)(&xs[ns][ii]) = val;
    }
    __syncthreads();
    int og = tid & 31, ng = tid >> 5;
    int j0 = og * 4, n0 = ng * 4;
    const float* wk = Wk + (size_t)t * HID * HID + j0;
    const float* wq = Wq + (size_t)t * HID * HID + j0;
    const float* wv = Wv + (size_t)t * HID * HID + j0;
    float aK[4][4] = {{0}}, aQ[4][4] = {{0}}, aV[4][4] = {{0}};
    for (int i = 0; i < HID; i += 4) {
        float4 xr[4];
#pragma unroll
        for (int nn = 0; nn < 4; ++nn) xr[nn] = *(const float4*)(&xs[n0 + nn][i]);
#pragma unroll
        for (int ii = 0; ii < 4; ++ii) {
            float4 wkv = *(const float4*)(wk + (size_t)(i + ii) * HID);
            float4 wqv = *(const float4*)(wq + (size_t)(i + ii) * HID);
            float4 wvv = *(const float4*)(wv + (size_t)(i + ii) * HID);
#pragma unroll
            for (int nn = 0; nn < 4; ++nn) {
                float xv = ((const float*)&xr[nn])[ii];
                aK[nn][0] = fmaf(xv, wkv.x, aK[nn][0]);
                aK[nn][1] = fmaf(xv, wkv.y, aK[nn][1]);
                aK[nn][2] = fmaf(xv, wkv.z, aK[nn][2]);
                aK[nn][3] = fmaf(xv, wkv.w, aK[nn][3]);
                aQ[nn][0] = fmaf(xv, wqv.x, aQ[nn][0]);
                aQ[nn][1] = fmaf(xv, wqv.y, aQ[nn][1]);
                aQ[nn][2] = fmaf(xv, wqv.z, aQ[nn][2]);
                aQ[nn][3] = fmaf(xv, wqv.w, aQ[nn][3]);
                aV[nn][0] = fmaf(xv, wvv.x, aV[nn][0]);
                aV[nn][1] = fmaf(xv, wvv.y, aV[nn][1]);
                aV[nn][2] = fmaf(xv, wvv.z, aV[nn][2]);
                aV[nn][3] = fmaf(xv, wvv.w, aV[nn][3]);
            }
        }
    }
#pragma unroll
    for (int nn = 0; nn < 4; ++nn) {
        int node = nodes[n0 + nn];
        if (node < 0) continue;
        size_t o = (size_t)node * HID + j0;
        *(float4*)(K + o) = make_float4(aK[nn][0], aK[nn][1], aK[nn][2], aK[nn][3]);
        *(float4*)(Q + o) = make_float4(aQ[nn][0], aQ[nn][1], aQ[nn][2], aQ[nn][3]);
        *(float4*)(V + o) = make_float4(aV[nn][0], aV[nn][1], aV[nn][2], aV[nn][3]);
    }
}

// ---------- tiled GEMM, 1 matrix; perm==null -> identity rows, type 0 ----------
__global__ __launch_bounds__(256) void gemm1_kernel(
    const float* __restrict__ x, const int* __restrict__ perm, const int* __restrict__ ntype,
    const float* __restrict__ W, const float* __restrict__ bias, float* __restrict__ out) {
    __shared__ float xs[TILE][HID];
    __shared__ int nodes[TILE];
    int tid = threadIdx.x;
    if (tid < TILE) {
        int n;
        if (perm) n = perm[blockIdx.x * TILE + tid];
        else { n = blockIdx.x * TILE + tid; if (n >= N_NODES) n = -1; }
        nodes[tid] = n;
    }
    __syncthreads();
    if (nodes[0] < 0) return;
    int t = perm ? ntype[nodes[0]] : 0;
#pragma unroll
    for (int c = 0; c < 4; ++c) {
        int v = tid + c * 256;
        int ns = v >> 5, ii = (v & 31) * 4;
        int node = nodes[ns];
        float4 val = (node >= 0) ? *(const float4*)(x + (size_t)node * HID + ii)
                                 : make_float4(0.f, 0.f, 0.f, 0.f);
        *(float4*)(&xs[ns][ii]) = val;
    }
    __syncthreads();
    int og = tid & 31, ng = tid >> 5;
    int j0 = og * 4, n0 = ng * 4;
    const float* w = W + (size_t)t * HID * HID + j0;
    float acc[4][4] = {{0}};
    for (int i = 0; i < HID; i += 4) {
        float4 xr[4];
#pragma unroll
        for (int nn = 0; nn < 4; ++nn) xr[nn] = *(const float4*)(&xs[n0 + nn][i]);
#pragma unroll
        for (int ii = 0; ii < 4; ++ii) {
            float4 wv = *(const float4*)(w + (size_t)(i + ii) * HID);
#pragma unroll
            for (int nn = 0; nn < 4; ++nn) {
                float xv = ((const float*)&xr[nn])[ii];
                acc[nn][0] = fmaf(xv, wv.x, acc[nn][0]);
                acc[nn][1] = fmaf(xv, wv.y, acc[nn][1]);
                acc[nn][2] = fmaf(xv, wv.z, acc[nn][2]);
                acc[nn][3] = fmaf(xv, wv.w, acc[nn][3]);
            }
        }
    }
    float4 bv = make_float4(0.f, 0.f, 0.f, 0.f);
    if (bias) bv = *(const float4*)(bias + j0);
#pragma unroll
    for (int nn = 0; nn < 4; ++nn) {
        int node = nodes[n0 + nn];
        if (node < 0) continue;
        size_t o = (size_t)node * HID + j0;
        *(float4*)(out + o) = make_float4(acc[nn][0] + bv.x, acc[nn][1] + bv.y,
                                          acc[nn][2] + bv.z, acc[nn][3] + bv.w);
    }
}

// ---------- edge kernels (unchanged from round 0) ----------
__global__ void edge_score_kernel(const float* __restrict__ K, const float* __restrict__ Q,
                                  const int* __restrict__ src, const int* __restrict__ dst,
                                  const int* __restrict__ etype,
                                  const float* __restrict__ Watt, const float* __restrict__ pri,
                                  float* __restrict__ a_out, unsigned int* __restrict__ amax) {
    int gid = blockIdx.x * 16 + (threadIdx.x >> 4);
    int lane = threadIdx.x & 15;
    int e = gid >> 3, h = gid & 7;
    int s = src[e], d = dst[e], r = etype[e];
    float k_i = K[s * HID + h * HS + lane];
    float q_o = Q[d * HID + h * HS + lane];
    const float* W = Watt + (size_t)(h * NR + r) * HS * HS;
    float kw = 0.f;
#pragma unroll
    for (int i = 0; i < HS; ++i)
        kw = fmaf(__shfl(k_i, i, HS), W[i * HS + lane], kw);
    float val = kw * q_o;
#pragma unroll
    for (int off = 8; off; off >>= 1) val += __shfl_xor(val, off, 16);
    if (lane == 0) {
        float a = val * pri[h * NR + r] * 0.25f;
        a_out[e * NH + h] = a;
        atomicMax(&amax[d * NH + h], enc_f(a));
    }
}

__global__ void softmax_den_kernel(float* __restrict__ a, const int* __restrict__ dst,
                                   const unsigned int* __restrict__ amax,
                                   float* __restrict__ den) {
    int i = blockIdx.x * 256 + threadIdx.x;
    int e = i >> 3, h = i & 7;
    int d = dst[e];
    float m = dec_f(amax[d * NH + h]);
    float ex = expf(a[i] - m);
    a[i] = ex;
    atomicAdd(&den[d * NH + h], ex);
}

__global__ void message_kernel(const float* __restrict__ V, const int* __restrict__ src,
                               const int* __restrict__ dst, const int* __restrict__ etype,
                               const float* __restrict__ Wmsg, const float* __restrict__ ex,
                               const float* __restrict__ den, float* __restrict__ agg) {
    int gid = blockIdx.x * 16 + (threadIdx.x >> 4);
    int lane = threadIdx.x & 15;
    int e = gid >> 3, h = gid & 7;
    int s = src[e], d = dst[e], r = etype[e];
    float v_i = V[s * HID + h * HS + lane];
    const float* W = Wmsg + (size_t)(h * NR + r) * HS * HS;
    float m = 0.f;
#pragma unroll
    for (int i = 0; i < HS; ++i)
        m = fmaf(__shfl(v_i, i, HS), W[i * HS + lane], m);
    float alpha = ex[e * NH + h] / (den[d * NH + h] + 1e-16f);
    atomicAdd(&agg[d * HID + h * HS + lane], alpha * m);
}

// ---------- epilogue: SiLU + gated residual + LayerNorm (matvec already done) ----------
__global__ void out_elem_kernel(const float* __restrict__ pre, const float* __restrict__ xin,
                                const int* __restrict__ ntype, const float* __restrict__ skip,
                                const float* __restrict__ g, const float* __restrict__ b,
                                float* __restrict__ xout) {
    int n = blockIdx.x, j = threadIdx.x;
    __shared__ float red[HID];
    int t = ntype[n];
    float acc = pre[n * HID + j];
    float sil = acc / (1.f + expf(-acc));
    float al = 1.f / (1.f + expf(-skip[t]));
    float o = sil * al + xin[n * HID + j] * (1.f - al);
    red[j] = o; __syncthreads();
    for (int s2 = 64; s2; s2 >>= 1) { if (j < s2) red[j] += red[j + s2]; __syncthreads(); }
    float mu = red[0] * (1.f / HID);
    __syncthreads();
    float dv = o - mu;
    red[j] = dv * dv; __syncthreads();
    for (int s2 = 64; s2; s2 >>= 1) { if (j < s2) red[j] += red[j + s2]; __syncthreads(); }
    float var = red[0] * (1.f / HID);
    xout[n * HID + j] = dv * rsqrtf(var + 1e-5f) * g[j] + b[j];
}

extern "C" void kernel_launch(void* const* d_in, const int* in_sizes, int n_in,
                              void* d_out, int out_size, void* d_ws, size_t ws_size,
                              hipStream_t stream) {
    const float* x     = (const float*)d_in[0];
    const int*   eidx  = (const int*)d_in[1];
    const int*   ntype = (const int*)d_in[2];
    const int*   etype = (const int*)d_in[3];
    const float* Wk    = (const float*)d_in[4];
    const float* Wq    = (const float*)d_in[5];
    const float* Wv    = (const float*)d_in[6];
    const float* Wa    = (const float*)d_in[7];
    const float* pri   = (const float*)d_in[8];
    const float* Watt  = (const float*)d_in[9];
    const float* Wmsg  = (const float*)d_in[10];
    const float* skip  = (const float*)d_in[11];
    const float* ln_g  = (const float*)d_in[12];
    const float* ln_b  = (const float*)d_in[13];
    const float* Wff   = (const float*)d_in[14];
    const float* bff   = (const float*)d_in[15];
    const int* src = eidx;
    const int* dst = eidx + N_EDGES;

    char* ws = (char*)d_ws;
    size_t szN = (size_t)N_NODES * HID * sizeof(float);       // 25.6 MB
    float* embA = (float*)(ws);
    float* Kb   = (float*)(ws + szN);                          // K, later agg
    float* Qb   = (float*)(ws + 2 * szN);                      // Q, later layer-1 out
    float* Vb   = (float*)(ws + 3 * szN);                      // V, later pre-activation
    char*  p    = ws + 4 * szN;
    float* abuf = (float*)p;                 p += (size_t)N_EDGES * NH * 4;   // 12.8 MB
    unsigned int* amax = (unsigned int*)p;   p += (size_t)N_NODES * NH * 4;   // 1.6 MB
    float* den  = (float*)p;                 p += (size_t)N_NODES * NH * 4;   // 1.6 MB
    int* perm   = (int*)p;                   p += (size_t)PERM_SZ * 4;        // 201 KB
    int* cnt    = (int*)p;                   p += TN * 4;
    int* cursor = (int*)p;                   p += TN * 4;

    // counting sort by node type (padded segments of TILE)
    hipMemsetAsync(cnt, 0, TN * 4, stream);
    hipMemsetAsync(perm, 0xFF, (size_t)PERM_SZ * 4, stream);
    hist_kernel<<<(N_NODES + 255) / 256, 256, 0, stream>>>(ntype, cnt);
    scan_kernel<<<1, 64, 0, stream>>>(cnt, cursor);
    scatter_kernel<<<(N_NODES + 255) / 256, 256, 0, stream>>>(ntype, cursor, perm);

    for (int l = 0; l < 2; ++l) {
        const float* xin = l ? embA : x;
        float* xout = l ? Qb : embA;
        const float* Wk_l   = Wk   + (size_t)l * TN * HID * HID;
        const float* Wq_l   = Wq   + (size_t)l * TN * HID * HID;
        const float* Wv_l   = Wv   + (size_t)l * TN * HID * HID;
        const float* Wa_l   = Wa   + (size_t)l * TN * HID * HID;
        const float* Watt_l = Watt + (size_t)l * NH * NR * HS * HS;
        const float* Wmsg_l = Wmsg + (size_t)l * NH * NR * HS * HS;
        const float* pri_l  = pri  + (size_t)l * NH * NR;
        const float* skip_l = skip + (size_t)l * TN;
        const float* g_l    = ln_g + (size_t)l * HID;
        const float* b_l    = ln_b + (size_t)l * HID;

        hipMemsetAsync(den, 0, (size_t)N_NODES * NH * 4, stream);
        init_amax_kernel<<<(N_NODES * NH + 255) / 256, 256, 0, stream>>>(amax);
        gemm3_kernel<<<MAXTILES, 256, 0, stream>>>(xin, perm, ntype, Wk_l, Wq_l, Wv_l,
                                                   Kb, Qb, Vb);
        edge_score_kernel<<<N_EDGES * NH / 16, 256, 0, stream>>>(Kb, Qb, src, dst, etype,
                                                                 Watt_l, pri_l, abuf, amax);
        hipMemsetAsync(Kb, 0, szN, stream);   // Kb becomes agg
        softmax_den_kernel<<<N_EDGES * NH / 256, 256, 0, stream>>>(abuf, dst, amax, den);
        message_kernel<<<N_EDGES * NH / 16, 256, 0, stream>>>(Vb, src, dst, etype,
                                                              Wmsg_l, abuf, den, Kb);
        // Wa typed GEMM: agg(Kb) -> pre(Vb)  (V dead after message)
        gemm1_kernel<<<MAXTILES, 256, 0, stream>>>(Kb, perm, ntype, Wa_l, nullptr, Vb);
        out_elem_kernel<<<N_NODES, HID, 0, stream>>>(Vb, xin, ntype, skip_l, g_l, b_l, xout);
    }
    // final FF: emb(Qb) @ Wff + bff -> d_out   (untyped, identity rows)
    gemm1_kernel<<<(N_NODES + TILE - 1) / TILE, 256, 0, stream>>>(Qb, nullptr, ntype, Wff,
                                                                  bff, (float*)d_out);
}